// Round 5
// baseline (4852.377 us; speedup 1.0000x reference)
//
#include <hip/hip_runtime.h>
#include <hip/hip_cooperative_groups.h>

// Sinkhorn EMD (ApproximatedEMDLoss), B=16, N=2048, D=3, eps=0.01, 50 iters.
//
// R4: single persistent cooperative kernel. R1-R3 all measured 24.2-24.3us
// per pass across wildly different instruction mixes -> per-pass floor is
// launch/drain overhead (and/or trans-pipe), not VALU issue. Fuse all 102
// passes into one kernel with grid.sync() between half-iterations; stage both
// point sets in LDS once (w-slot of each float4 carries the Sinkhorn weight,
// refreshed per phase). Cross-block vectors s/p/q go through global memory
// with agent-scope atomics (per-XCD L2 is not coherent within one kernel).
//
// Math: with s_j = sum_i K_ij,  u = r/(K w) (w = v/s),  v = c*s/(K^T u);
// and v/s = c/q, so only raw matvec results p,q ever feed the next phase.

namespace cg = cooperative_groups;

namespace {
constexpr int kB = 16;
constexpr int kN = 2048;
constexpr int NT = 512;                       // threads per block
constexpr int SPLITS = 8;                     // j-splits per row
constexpr int CHUNK = kN / SPLITS;            // 256
constexpr int BPB = 32;                       // blocks per batch
constexpr int GRID = kB * BPB;                // 512 = 2 blocks/CU (LDS-bound)
constexpr int ROWS = kN / BPB;                // 64 rows per block per direction
constexpr float kR = 1.0f / (float)kN;
constexpr float kScale = 144.26950408889634f; // 100 * log2(e)

__device__ __forceinline__ int skew(int j) { return j + (j >> 8); }

__device__ __forceinline__ float ld_agent(const float* p) {
  return __hip_atomic_load(p, __ATOMIC_RELAXED, __HIP_MEMORY_SCOPE_AGENT);
}
__device__ __forceinline__ void st_agent(float* p, float v) {
  __hip_atomic_store(p, v, __ATOMIC_RELAXED, __HIP_MEMORY_SCOPE_AGENT);
}
}  // namespace

__global__ __launch_bounds__(NT, 4) void emd_fused(
    const float* __restrict__ pc1, const float* __restrict__ pc2,
    float* __restrict__ s, float* __restrict__ p, float* __restrict__ q,
    float* __restrict__ out) {
  __shared__ float4 LX[kN + SPLITS];   // x points (scaled), w = weight slot
  __shared__ float4 LY[kN + SPLITS];   // y points (scaled), w = weight slot
  __shared__ float wred[NT / 64];
  cg::grid_group grid = cg::this_grid();

  const int b = blockIdx.x >> 5;                    // / BPB
  const int rowbase = (blockIdx.x & 31) * ROWS;
  const int split = threadIdx.x & (SPLITS - 1);
  const int row = rowbase + (threadIdx.x >> 3);     // this thread's row
  const float* xp = pc1 + b * kN * 3;
  const float* yp = pc2 + b * kN * 3;

  // one-time stage: both point sets, pre-scaled by 100*log2(e)
  for (int j = threadIdx.x; j < kN; j += NT) {
    LX[skew(j)] = make_float4(xp[3 * j] * kScale, xp[3 * j + 1] * kScale,
                              xp[3 * j + 2] * kScale, 1.0f);   // w=1 for s-pass
    LY[skew(j)] = make_float4(yp[3 * j] * kScale, yp[3 * j + 1] * kScale,
                              yp[3 * j + 2] * kScale, 0.0f);
  }
  __syncthreads();

  const float4 rx = LX[skew(row)];   // row point, x-orientation
  const float4 ry = LY[skew(row)];   // row point, y-orientation

  auto sweep = [&](const float4* Lc, float4 rpt) -> float {
    const float4* c = Lc + split * (CHUNK + 1);     // skewed chunk base
    float acc = 0.f;
#pragma unroll 8
    for (int k = 0; k < CHUNK; ++k) {
      float4 yw = c[k];
      float dx = rpt.x - yw.x, dy = rpt.y - yw.y, dz = rpt.z - yw.z;
      float d2 = fmaf(dx, dx, fmaf(dy, dy, dz * dz));
      acc = fmaf(__builtin_amdgcn_exp2f(-__builtin_amdgcn_sqrtf(d2)), yw.w, acc);
    }
    acc += __shfl_xor(acc, 1);
    acc += __shfl_xor(acc, 2);
    acc += __shfl_xor(acc, 4);
    return acc;                                     // valid on split==0
  };
  auto fill = [&](float4* L, const float* raw, float mult) {
    for (int j = threadIdx.x; j < kN; j += NT)
      L[skew(j)].w = mult / ld_agent(&raw[b * kN + j]);
  };

  // pass 0: s_j = sum_i K_ij  (rows = y, cols = x with w=1)
  { float a = sweep(LX, ry); if (split == 0) st_agent(&s[b * kN + row], a); }
  grid.sync();
  // p0 = K (1/s)
  fill(LY, s, 1.0f); __syncthreads();
  { float a = sweep(LY, rx); if (split == 0) st_agent(&p[b * kN + row], a); }
  grid.sync();
  // q0 = K^T (kR/p)
  fill(LX, p, kR); __syncthreads();
  { float a = sweep(LX, ry); if (split == 0) st_agent(&q[b * kN + row], a); }
  grid.sync();

  for (int it = 1; it < 50; ++it) {
    fill(LY, q, kR); __syncthreads();
    { float a = sweep(LY, rx); if (split == 0) st_agent(&p[b * kN + row], a); }
    grid.sync();
    fill(LX, p, kR); __syncthreads();
    { float a = sweep(LX, ry); if (split == 0) st_agent(&q[b * kN + row], a); }
    grid.sync();
  }

  // loss = mean_b sum_ij u_i K_ij v_j C_ij ; u = kR/p, v_j = kR*s_j/q_j
  for (int j = threadIdx.x; j < kN; j += NT)
    LY[skew(j)].w = kR * ld_agent(&s[b * kN + j]) / ld_agent(&q[b * kN + j]);
  __syncthreads();
  const float u = kR / ld_agent(&p[b * kN + row]);
  float acc = 0.f;
  {
    const float4* c = LY + split * (CHUNK + 1);
#pragma unroll 8
    for (int k = 0; k < CHUNK; ++k) {
      float4 yw = c[k];
      float dx = rx.x - yw.x, dy = rx.y - yw.y, dz = rx.z - yw.z;
      float d2 = fmaf(dx, dx, fmaf(dy, dy, dz * dz));
      float ds = __builtin_amdgcn_sqrtf(d2);
      acc = fmaf(__builtin_amdgcn_exp2f(-ds) * ds, yw.w, acc);  // K*C*kScale * v
    }
  }
  acc *= u;
#pragma unroll
  for (int m = 1; m < 64; m <<= 1) acc += __shfl_xor(acc, m);
  if ((threadIdx.x & 63) == 0) wred[threadIdx.x >> 6] = acc;
  __syncthreads();
  if (threadIdx.x == 0) {
    float t = 0.f;
#pragma unroll
    for (int wv = 0; wv < NT / 64; ++wv) t += wred[wv];
    atomicAdd(out, t * (1.0f / (kScale * (float)kB)));
  }
}

extern "C" void kernel_launch(void* const* d_in, const int* in_sizes, int n_in,
                              void* d_out, int out_size, void* d_ws, size_t ws_size,
                              hipStream_t stream) {
  const float* pc1 = (const float*)d_in[0];  // x (rows i)
  const float* pc2 = (const float*)d_in[1];  // y (cols j); pc3 unused
  float* s = (float*)d_ws;                   // [B,N] column sums of K
  float* p = s + kB * kN;                    // [B,N] raw K w
  float* q = p + kB * kN;                    // [B,N] raw K^T u
  float* outp = (float*)d_out;

  hipMemsetAsync(d_out, 0, sizeof(float), stream);

  void* args[] = {(void*)&pc1, (void*)&pc2, (void*)&s,
                  (void*)&p,   (void*)&q,   (void*)&outp};
  hipLaunchCooperativeKernel((const void*)emd_fused, dim3(GRID), dim3(NT),
                             args, 0, stream);
}

// Round 6
// 2721.236 us; speedup vs baseline: 1.7832x; 1.7832x over previous
//
#include <hip/hip_runtime.h>

// Sinkhorn EMD (ApproximatedEMDLoss), B=16, N=2048, D=3, eps=0.01, 50 iters.
//
// R5: thread<->row, column-broadcast structure.
// R1-R3 post-mortem: 24us/pass was real compute, bound by LDS pipe
// (16 waves/CU x 256 ds_read_b128 x 12cyc = 20.5us) and issue port
// (trans ~8 cyc issue each). Fix both:
//  - each lane owns ONE row; row point lives in VGPRs all kernel.
//  - columns stored as packed float4 {x,y,z,w}*scale in global; the k-loop
//    address is wave-uniform -> s_load_dwordx4 (scalar cache), NO LDS.
//  - each pass's epilogue writes the NEXT pass's column weights into the
//    row array's .w slot (p-pass: packed_x[i].w = kR/p_i = u_i, which is
//    q-pass's weight AND the final u). No fill kernels at all.
//
// Math: s_j = sum_i K_ij;  w0 = 1/s;  p = K w  (u = kR/p);
//       q = K^T u  (v = kR*s/q; next w = v/s = kR/q).
// Loss = mean_b sum_ij u_i K_ij v_j C_ij.

namespace {
constexpr int kB = 16;
constexpr int kN = 2048;
constexpr int NT = 512;                 // 8 waves/block
constexpr int WAVES = NT / 64;          // 8 column-chunks
constexpr int CCHUNK = kN / WAVES;      // 256 columns per wave
constexpr int ROWS = 64;                // rows per block (one per lane)
constexpr int BPB = kN / ROWS;          // 32 blocks per batch
constexpr int GRID = kB * BPB;          // 512 blocks = 2/CU = 16 waves/CU
constexpr float kR = 1.0f / (float)kN;
constexpr float kScale = 144.26950408889634f;  // 100 * log2(e)
}  // namespace

// Build packed arrays: {x,y,z}*kScale, w = 1 for x (s-pass weights), 0 for y.
__global__ void emd_setup(const float* __restrict__ pc1,
                          const float* __restrict__ pc2,
                          float4* __restrict__ px, float4* __restrict__ py) {
  int i = blockIdx.x * blockDim.x + threadIdx.x;
  if (i < kB * kN) {
    px[i] = make_float4(pc1[3 * i] * kScale, pc1[3 * i + 1] * kScale,
                        pc1[3 * i + 2] * kScale, 1.0f);
    py[i] = make_float4(pc2[3 * i] * kScale, pc2[3 * i + 1] * kScale,
                        pc2[3 * i + 2] * kScale, 0.0f);
  }
}

// One matvec pass: out_row_sum = sum_cols exp2(-|r-c|) * c.w, then epilogue
// writes rows[i].w = mult / sum (the next pass's weight), and optionally s[].
template <bool STORE_S>
__global__ __launch_bounds__(NT, 4) void emd_pass(
    float4* __restrict__ rows,          // row points; .w overwritten in epilogue
    const float4* __restrict__ cols,    // column points + weights
    float* __restrict__ s_out,          // [B,N] only when STORE_S
    float mult) {
  __shared__ float partial[WAVES][ROWS];
  const int b = blockIdx.x >> 5;                 // / BPB
  const int rg = blockIdx.x & 31;
  const int lane = threadIdx.x & 63;
  const int wav = threadIdx.x >> 6;
  const int rowi = b * kN + rg * ROWS + lane;

  const float4 r = rows[rowi];                   // coalesced dwordx4
  // wave-uniform column base -> scalar loads in the k-loop
  const int wu = __builtin_amdgcn_readfirstlane(wav);
  const float4* cbase = cols + b * kN + wu * CCHUNK;

  float acc = 0.f;
#pragma unroll 4
  for (int k = 0; k < CCHUNK; ++k) {
    float4 c = cbase[k];                         // s_load_dwordx4 (uniform)
    float dx = r.x - c.x, dy = r.y - c.y, dz = r.z - c.z;
    float d2 = fmaf(dx, dx, fmaf(dy, dy, dz * dz));
    acc = fmaf(__builtin_amdgcn_exp2f(-__builtin_amdgcn_sqrtf(d2)), c.w, acc);
  }
  partial[wav][lane] = acc;
  __syncthreads();
  if (wav == 0) {
    float sum = partial[0][lane];
#pragma unroll
    for (int w2 = 1; w2 < WAVES; ++w2) sum += partial[w2][lane];
    if (STORE_S) s_out[rowi] = sum;
    reinterpret_cast<float*>(rows + rowi)[3] = mult / sum;  // next weights
  }
}

// loss = mean_b sum_ij u_i K_ij v_j C_ij; u_i = xrows[i].w (=kR/p),
// v_j = s_j * ycols[j].w (=kR*s_j/q_j); K*C = e*ds/kScale (scaled units).
__global__ __launch_bounds__(NT, 4) void emd_loss(
    const float4* __restrict__ xrows, const float4* __restrict__ ycols,
    const float* __restrict__ s, float* __restrict__ out) {
  __shared__ float partial[WAVES][ROWS];
  const int b = blockIdx.x >> 5;
  const int rg = blockIdx.x & 31;
  const int lane = threadIdx.x & 63;
  const int wav = threadIdx.x >> 6;
  const int rowi = b * kN + rg * ROWS + lane;

  const float4 r = xrows[rowi];                  // .w = u_i
  const int wu = __builtin_amdgcn_readfirstlane(wav);
  const float4* cbase = ycols + b * kN + wu * CCHUNK;
  const float* sbase = s + b * kN + wu * CCHUNK;

  float acc = 0.f;
#pragma unroll 4
  for (int k = 0; k < CCHUNK; ++k) {
    float4 c = cbase[k];
    float sj = sbase[k];                         // s_load_dword (uniform)
    float dx = r.x - c.x, dy = r.y - c.y, dz = r.z - c.z;
    float d2 = fmaf(dx, dx, fmaf(dy, dy, dz * dz));
    float ds = __builtin_amdgcn_sqrtf(d2);
    float e = __builtin_amdgcn_exp2f(-ds);
    acc = fmaf(e * ds, c.w * sj, acc);           // (K*C*kScale) * v_j
  }
  partial[wav][lane] = acc;
  __syncthreads();
  if (wav == 0) {
    float sum = partial[0][lane];
#pragma unroll
    for (int w2 = 1; w2 < WAVES; ++w2) sum += partial[w2][lane];
    float t = sum * r.w;                         // * u_i
#pragma unroll
    for (int m = 1; m < 64; m <<= 1) t += __shfl_xor(t, m);
    if (lane == 0) atomicAdd(out, t * (1.0f / (kScale * (float)kB)));
  }
}

extern "C" void kernel_launch(void* const* d_in, const int* in_sizes, int n_in,
                              void* d_out, int out_size, void* d_ws, size_t ws_size,
                              hipStream_t stream) {
  const float* pc1 = (const float*)d_in[0];  // x (rows i)
  const float* pc2 = (const float*)d_in[1];  // y (cols j); pc3 unused
  float4* px = (float4*)d_ws;                // [B*N] packed x: coords + w
  float4* py = px + kB * kN;                 // [B*N] packed y: coords + w
  float* s = (float*)(py + kB * kN);         // [B*N] column sums of K

  hipLaunchKernelGGL(emd_setup, dim3((kB * kN + 255) / 256), dim3(256), 0,
                     stream, pc1, pc2, px, py);

  // s-pass: s_j = sum_i K_ij (rows = y, cols = x with w=1);
  // epilogue: py.w = 1/s (= v0/s, first p-pass weights), s[] stored.
  hipLaunchKernelGGL((emd_pass<true>), dim3(GRID), dim3(NT), 0, stream,
                     py, px, s, 1.0f);
  for (int it = 0; it < 50; ++it) {
    // p-pass: p_i = sum_j K_ij * py.w ; epilogue px.w = kR/p = u_i
    hipLaunchKernelGGL((emd_pass<false>), dim3(GRID), dim3(NT), 0, stream,
                       px, py, (float*)nullptr, kR);
    // q-pass: q_j = sum_i K_ij * px.w ; epilogue py.w = kR/q (next w; v=s*py.w)
    hipLaunchKernelGGL((emd_pass<false>), dim3(GRID), dim3(NT), 0, stream,
                       py, px, (float*)nullptr, kR);
  }
  hipMemsetAsync(d_out, 0, sizeof(float), stream);
  hipLaunchKernelGGL(emd_loss, dim3(GRID), dim3(NT), 0, stream,
                     px, py, s, (float*)d_out);
}